// Round 7
// baseline (202.578 us; speedup 1.0000x reference)
//
#include <hip/hip_runtime.h>
#include <hip/hip_bf16.h>

namespace {

constexpr int B = 2, S = 2048, E = 512, H = 8, D = 64, HD = 512;
constexpr float SCALE = 0.125f;            // 1/sqrt(64)
constexpr float SL = 0.125f * 1.44269504f; // SCALE * log2(e)
constexpr int PLD = 40;                    // proj LDS row stride (bf16)

typedef __attribute__((ext_vector_type(8))) short bf16x8;
typedef __attribute__((ext_vector_type(4))) unsigned short u16x4;
typedef __attribute__((ext_vector_type(4))) float f32x4;
typedef __attribute__((ext_vector_type(4))) float float4v;

__device__ __forceinline__ ushort f2b(float x) {
  __hip_bfloat16 h = __float2bfloat16(x);
  return *reinterpret_cast<const ushort*>(&h);
}
__device__ __forceinline__ float b2f_u(ushort u) {
  __hip_bfloat16 h = *reinterpret_cast<const __hip_bfloat16*>(&u);
  return __bfloat162float(h);
}

// ---------------------------------------------------------------------------
// Prep: K (b,k,h,d) fp32 -> Kbf (b,h,k,d) bf16 ; V -> Vtbf (b,h,d,k) bf16.
__global__ __launch_bounds__(256) void prep_kv_kernel(
    const float* __restrict__ K, const float* __restrict__ V,
    ushort* __restrict__ Kbf, ushort* __restrict__ Vtbf) {
  __shared__ __align__(16) ushort Vn[64][76];
  const int bid = blockIdx.x;
  const int kt = bid & 31;
  const int bh = bid >> 5;
  const int b = bh >> 3, h = bh & 7;
  const int k0 = kt * 64;
  const int t = threadIdx.x;
#pragma unroll
  for (int i = 0; i < 4; ++i) {
    int c = i * 256 + t;
    int kk = c >> 4, d4 = (c & 15) * 4;
    size_t g = ((size_t)(b * 2048 + k0 + kk) * 8 + h) * 64 + d4;
    float4v kv = *(const float4v*)(K + g);
    float4v vv = *(const float4v*)(V + g);
    u16x4 kp = {f2b(kv.x), f2b(kv.y), f2b(kv.z), f2b(kv.w)};
    u16x4 vp = {f2b(vv.x), f2b(vv.y), f2b(vv.z), f2b(vv.w)};
    *(u16x4*)(Kbf + ((size_t)(bh * 2048 + k0 + kk)) * 64 + d4) = kp;
    *(u16x4*)&Vn[kk][d4] = vp;
  }
  __syncthreads();
#pragma unroll
  for (int i = 0; i < 2; ++i) {
    int c = i * 256 + t;
    int kc8 = (c & 7) * 8, d = c >> 3;
    union { ushort u[8]; bf16x8 v; } p;
#pragma unroll
    for (int j = 0; j < 8; ++j) p.u[j] = Vn[kc8 + j][d];
    *(bf16x8*)(Vtbf + ((size_t)(bh * 64 + d)) * 2048 + k0 + kc8) = p.v;
  }
}

// ---------------------------------------------------------------------------
// Prep: mask int32 (B,S,S) -> keep bits, keep[row*64+j] bit b = (mask==0) for k=32j+b.
__global__ __launch_bounds__(256) void prep_mask_kernel(
    const int* __restrict__ m, uint* __restrict__ keep) {
  int gid = blockIdx.x * 256 + threadIdx.x;  // 262144 total
  int row = gid >> 6, j = gid & 63;
  const int4* p = (const int4*)(m + (size_t)row * 2048 + j * 32);
  uint w = 0;
#pragma unroll
  for (int q = 0; q < 8; ++q) {
    int4 v = p[q];
    w |= (uint)(v.x == 0) << (q * 4 + 0);
    w |= (uint)(v.y == 0) << (q * 4 + 1);
    w |= (uint)(v.z == 0) << (q * 4 + 2);
    w |= (uint)(v.w == 0) << (q * 4 + 3);
  }
  keep[gid] = w;
}

// ---------------------------------------------------------------------------
// Prep: W (512x512 fp32, [k][n]) -> Wt (bf16 [n][k]) for Wq (y=0) and Wo (y=1).
__global__ __launch_bounds__(256) void prep_wt_kernel(
    const float* __restrict__ Wq, const float* __restrict__ Wo,
    ushort* __restrict__ Wtq, ushort* __restrict__ Wto) {
  __shared__ __align__(16) ushort T[64][68];
  const float* Wsrc = blockIdx.y ? Wo : Wq;
  ushort* Wdst = blockIdx.y ? Wto : Wtq;
  const int k0 = (blockIdx.x & 7) * 64, n0 = (blockIdx.x >> 3) * 64;
  const int t = threadIdx.x;
#pragma unroll
  for (int i = 0; i < 4; ++i) {
    int c = i * 256 + t;
    int kk = c >> 4, n4 = (c & 15) * 4;
    float4v v = *(const float4v*)(Wsrc + (size_t)(k0 + kk) * 512 + n0 + n4);
    u16x4 p = {f2b(v.x), f2b(v.y), f2b(v.z), f2b(v.w)};
    *(u16x4*)&T[kk][n4] = p;
  }
  __syncthreads();
#pragma unroll
  for (int i = 0; i < 2; ++i) {
    int c = i * 256 + t;
    int n = c >> 3, k8 = (c & 7) * 8;
    union { ushort u[8]; bf16x8 v; } p;
#pragma unroll
    for (int j = 0; j < 8; ++j) p.u[j] = T[k8 + j][n];
    *(bf16x8*)(Wdst + (size_t)(n0 + n) * 512 + k0 + k8) = p.v;
  }
}

// ---------------------------------------------------------------------------
// proj_q: Qbf[b][h][q][d] (bf16) = inputs @ Wq ; A fp32 hi/lo split, Wt bf16 [n][k].
__global__ __launch_bounds__(256) void proj_q_kernel(
    const float* __restrict__ A, const ushort* __restrict__ Wt, ushort* __restrict__ Qbf) {
  __shared__ __align__(16) ushort As_hi[64][PLD];
  __shared__ __align__(16) ushort As_lo[64][PLD];
  __shared__ __align__(16) ushort Ws[64][PLD];

  const int tid = threadIdx.x;
  const int lane = tid & 63;
  const int w = tid >> 6;
  const int col = lane & 15;
  const int quad = lane >> 4;
  const int m0 = blockIdx.y * 64;
  const int n0 = blockIdx.x * 64;
  const int wm = (w & 1) * 32;
  const int wn = (w >> 1) * 32;
  const int ar = tid >> 2;
  const int ak = (tid & 3) * 8;
  const int wn2 = tid >> 2;
  const int wkc = (tid & 3) * 8;

  f32x4 acc[2][2];
#pragma unroll
  for (int i = 0; i < 2; ++i)
#pragma unroll
    for (int j = 0; j < 2; ++j) acc[i][j] = f32x4{0.f, 0.f, 0.f, 0.f};

  for (int kt = 0; kt < 16; ++kt) {
    const int k0 = kt * 32;
    {
      const float* Ap = A + (size_t)(m0 + ar) * 512 + k0 + ak;
      float4v v0 = *(const float4v*)Ap;
      float4v v1 = *(const float4v*)(Ap + 4);
      float a[8] = {v0.x, v0.y, v0.z, v0.w, v1.x, v1.y, v1.z, v1.w};
      union { ushort u[8]; bf16x8 v; } hi, lo;
#pragma unroll
      for (int j = 0; j < 8; ++j) {
        ushort hh = f2b(a[j]);
        hi.u[j] = hh;
        lo.u[j] = f2b(a[j] - b2f_u(hh));
      }
      *(bf16x8*)&As_hi[ar][ak] = hi.v;
      *(bf16x8*)&As_lo[ar][ak] = lo.v;
    }
    *(bf16x8*)&Ws[wn2][wkc] = *(const bf16x8*)(Wt + (size_t)(n0 + wn2) * 512 + k0 + wkc);
    __syncthreads();

    bf16x8 ah[2], al[2], wb[2];
#pragma unroll
    for (int i = 0; i < 2; ++i) {
      ah[i] = *(const bf16x8*)&As_hi[wm + i * 16 + col][quad * 8];
      al[i] = *(const bf16x8*)&As_lo[wm + i * 16 + col][quad * 8];
    }
#pragma unroll
    for (int j = 0; j < 2; ++j)
      wb[j] = *(const bf16x8*)&Ws[wn + j * 16 + col][quad * 8];
#pragma unroll
    for (int i = 0; i < 2; ++i)
#pragma unroll
      for (int j = 0; j < 2; ++j) {
        acc[i][j] = __builtin_amdgcn_mfma_f32_16x16x32_bf16(ah[i], wb[j], acc[i][j], 0, 0, 0);
        acc[i][j] = __builtin_amdgcn_mfma_f32_16x16x32_bf16(al[i], wb[j], acc[i][j], 0, 0, 0);
      }
    __syncthreads();
  }

#pragma unroll
  for (int i = 0; i < 2; ++i)
#pragma unroll
    for (int j = 0; j < 2; ++j)
#pragma unroll
      for (int r = 0; r < 4; ++r) {
        int m = m0 + wm + i * 16 + quad * 4 + r;
        int n = n0 + wn + j * 16 + col;
        int b = m >> 11, q = m & 2047, h = n >> 6, dd = n & 63;
        Qbf[((size_t)(b * 8 + h) * 2048 + q) * 64 + dd] = f2b(acc[i][j][r]);
      }
}

// ---------------------------------------------------------------------------
// proj_out: out fp32 = attnb (bf16) @ Wo ; Wt bf16 [n][k].
__global__ __launch_bounds__(256) void proj_out_kernel(
    const ushort* __restrict__ A, const ushort* __restrict__ Wt, float* __restrict__ C) {
  __shared__ __align__(16) ushort As[64][PLD];
  __shared__ __align__(16) ushort Ws[64][PLD];

  const int tid = threadIdx.x;
  const int lane = tid & 63;
  const int w = tid >> 6;
  const int col = lane & 15;
  const int quad = lane >> 4;
  const int m0 = blockIdx.y * 64;
  const int n0 = blockIdx.x * 64;
  const int wm = (w & 1) * 32;
  const int wn = (w >> 1) * 32;
  const int ar = tid >> 2;
  const int ak = (tid & 3) * 8;
  const int wn2 = tid >> 2;
  const int wkc = (tid & 3) * 8;

  f32x4 acc[2][2];
#pragma unroll
  for (int i = 0; i < 2; ++i)
#pragma unroll
    for (int j = 0; j < 2; ++j) acc[i][j] = f32x4{0.f, 0.f, 0.f, 0.f};

  for (int kt = 0; kt < 16; ++kt) {
    const int k0 = kt * 32;
    *(bf16x8*)&As[ar][ak] = *(const bf16x8*)(A + (size_t)(m0 + ar) * 512 + k0 + ak);
    *(bf16x8*)&Ws[wn2][wkc] = *(const bf16x8*)(Wt + (size_t)(n0 + wn2) * 512 + k0 + wkc);
    __syncthreads();

    bf16x8 ah[2], wb[2];
#pragma unroll
    for (int i = 0; i < 2; ++i)
      ah[i] = *(const bf16x8*)&As[wm + i * 16 + col][quad * 8];
#pragma unroll
    for (int j = 0; j < 2; ++j)
      wb[j] = *(const bf16x8*)&Ws[wn + j * 16 + col][quad * 8];
#pragma unroll
    for (int i = 0; i < 2; ++i)
#pragma unroll
      for (int j = 0; j < 2; ++j)
        acc[i][j] = __builtin_amdgcn_mfma_f32_16x16x32_bf16(ah[i], wb[j], acc[i][j], 0, 0, 0);
    __syncthreads();
  }

#pragma unroll
  for (int i = 0; i < 2; ++i)
#pragma unroll
    for (int j = 0; j < 2; ++j)
#pragma unroll
      for (int r = 0; r < 4; ++r)
        C[(size_t)(m0 + wm + i * 16 + quad * 4 + r) * 512 + n0 + wn + j * 16 + col] =
            acc[i][j][r];
}

// ---------------------------------------------------------------------------
// Flash attention, S^T orientation: per-tile scores computed as K·Q^T so each
// lane owns 32 scores of a single q-row (softmax in-lane + 2 shuffles; P store
// becomes 8x ds_write_b64). Mask applied post-exp via packed keep-bits.
__global__ __launch_bounds__(256) void flash_attn_kernel(
    const ushort* __restrict__ Qbf, const ushort* __restrict__ Kbf,
    const ushort* __restrict__ Vtbf, const uint* __restrict__ keep,
    ushort* __restrict__ Op) {
  __shared__ __align__(16) ushort Ks[128][72];
  __shared__ __align__(16) ushort Vt[64][136];
  __shared__ __align__(16) ushort PQ[64][136];  // Q staged first; reused as P[q][k]

  const int bid = blockIdx.x;
  const int qt = bid & 31;
  const int bh = bid >> 5;
  const int b = bh >> 3, h = bh & 7;
  const int q0 = qt * 64;
  const int tid = threadIdx.x;
  const int lane = tid & 63;
  const int w = tid >> 6;
  const int col = lane & 15;
  const int quad = lane >> 4;
  const int quad4 = quad * 4;

  // stage Q (64x64 bf16, contiguous) into PQ[:][0..63]
  const ushort* Qt = Qbf + (size_t)(bh * 2048 + q0) * 64;
#pragma unroll
  for (int i = 0; i < 2; ++i) {
    int c = i * 256 + tid;
    *(bf16x8*)&PQ[c >> 3][(c & 7) * 8] = *(const bf16x8*)(Qt + c * 8);
  }
  __syncthreads();
  // hoist Q B-fragments (before PQ is reused as P storage)
  const bf16x8 qb0 = *(const bf16x8*)&PQ[w * 16 + col][quad * 8];
  const bf16x8 qb1 = *(const bf16x8*)&PQ[w * 16 + col][32 + quad * 8];

  f32x4 oacc[4];
#pragma unroll
  for (int c = 0; c < 4; ++c) oacc[c] = f32x4{0.f, 0.f, 0.f, 0.f};
  float m = -INFINITY, l = 0.f;

  // keep-bit row for this lane's q-column
  const uint4* kr = (const uint4*)keep + ((size_t)(b * 2048 + q0 + w * 16 + col)) * 16;

  for (int kt = 0; kt < 16; ++kt) {
    const int k0 = kt * 128;
    const ushort* Ktile = Kbf + (size_t)(bh * 2048 + k0) * 64;
    const ushort* Vtile = Vtbf + (size_t)(bh * 64) * 2048 + k0;
#pragma unroll
    for (int i = 0; i < 4; ++i) {
      int c = i * 256 + tid;
      *(bf16x8*)&Ks[c >> 3][(c & 7) * 8] = *(const bf16x8*)(Ktile + c * 8);
      int d = c >> 4, k8 = (c & 15) * 8;
      *(bf16x8*)&Vt[d][k8] = *(const bf16x8*)(Vtile + (size_t)d * 2048 + k8);
    }
    __syncthreads();

    const uint4 mw = kr[kt];
    const uint mwords[4] = {mw.x, mw.y, mw.z, mw.w};

    // S^T: 128 k-rows x 16 q-cols per wave
    f32x4 sc[8];
#pragma unroll
    for (int t = 0; t < 8; ++t) sc[t] = f32x4{0.f, 0.f, 0.f, 0.f};
#pragma unroll
    for (int t = 0; t < 8; ++t) {
      bf16x8 ka0 = *(const bf16x8*)&Ks[t * 16 + col][quad * 8];
      bf16x8 ka1 = *(const bf16x8*)&Ks[t * 16 + col][32 + quad * 8];
      sc[t] = __builtin_amdgcn_mfma_f32_16x16x32_bf16(ka0, qb0, sc[t], 0, 0, 0);
      sc[t] = __builtin_amdgcn_mfma_f32_16x16x32_bf16(ka1, qb1, sc[t], 0, 0, 0);
    }

    // in-lane max (raw scores; scale after — SL > 0)
    float mx = -INFINITY;
#pragma unroll
    for (int t = 0; t < 8; ++t)
#pragma unroll
      for (int r = 0; r < 4; ++r) mx = fmaxf(mx, sc[t][r]);
    mx *= SL;
    mx = fmaxf(mx, __shfl_xor(mx, 16));
    mx = fmaxf(mx, __shfl_xor(mx, 32));

    const float mn = fmaxf(m, mx);
    const float alpha = exp2f(m - mn);
    m = mn;

    // p = 2^(s*SL - mn), zero masked, in-lane sum
    float rs = 0.f;
#pragma unroll
    for (int t = 0; t < 8; ++t) {
      uint sh = mwords[t >> 1] >> ((t & 1) * 16 + quad4);
#pragma unroll
      for (int r = 0; r < 4; ++r) {
        float p = exp2f(fmaf(sc[t][r], SL, -mn));
        p = ((sh >> r) & 1u) ? p : 0.f;
        sc[t][r] = p;
        rs += p;
      }
    }
    rs += __shfl_xor(rs, 16);
    rs += __shfl_xor(rs, 32);
    l = l * alpha + rs;

    // rescale O (rows quad4+r) with alpha from lane quad4+r
    float alO[4];
#pragma unroll
    for (int r = 0; r < 4; ++r) alO[r] = __shfl(alpha, quad4 + r);
#pragma unroll
    for (int c = 0; c < 4; ++c)
#pragma unroll
      for (int r = 0; r < 4; ++r) oacc[c][r] *= alO[r];

    // store P transposed: Ps[q][k], 4 consecutive k per lane -> b64
#pragma unroll
    for (int t = 0; t < 8; ++t) {
      u16x4 pk = {f2b(sc[t][0]), f2b(sc[t][1]), f2b(sc[t][2]), f2b(sc[t][3])};
      *(u16x4*)&PQ[w * 16 + col][t * 16 + quad4] = pk;
    }
    __threadfence_block();

    bf16x8 pa[4];
#pragma unroll
    for (int kb = 0; kb < 4; ++kb)
      pa[kb] = *(const bf16x8*)&PQ[w * 16 + col][kb * 32 + quad * 8];
#pragma unroll
    for (int c = 0; c < 4; ++c)
#pragma unroll
      for (int kb = 0; kb < 4; ++kb) {
        bf16x8 vb = *(const bf16x8*)&Vt[c * 16 + col][kb * 32 + quad * 8];
        oacc[c] = __builtin_amdgcn_mfma_f32_16x16x32_bf16(pa[kb], vb, oacc[c], 0, 0, 0);
      }
    __syncthreads();
  }

  const float inv = 1.f / l;
  float invO[4];
#pragma unroll
  for (int r = 0; r < 4; ++r) invO[r] = __shfl(inv, quad4 + r);
#pragma unroll
  for (int c = 0; c < 4; ++c)
#pragma unroll
    for (int r = 0; r < 4; ++r)
      Op[(size_t)(b * S + q0 + w * 16 + quad4 + r) * HD + h * D + c * 16 + col] =
          f2b(oacc[c][r] * invO[r]);
}

}  // namespace

extern "C" void kernel_launch(void* const* d_in, const int* in_sizes, int n_in,
                              void* d_out, int out_size, void* d_ws, size_t ws_size,
                              hipStream_t stream) {
  const float* inputs = (const float*)d_in[0];   // (B,S,E)
  const float* keys   = (const float*)d_in[1];   // (B,S,H,D)
  const float* values = (const float*)d_in[2];   // (B,S,H,D)
  const float* wq     = (const float*)d_in[3];   // (E, HD)
  const float* wo     = (const float*)d_in[4];   // (HD, E)
  const int*   maskp  = (const int*)d_in[5];     // (B,S,S) bool as int32
  float* out = (float*)d_out;                    // (B,S,E)

  // d_out (8 MB) doubles as scratch for K/V bf16 until proj_out overwrites it.
  ushort* Kbf  = (ushort*)d_out;                 // (B,H,S,D) bf16, 4 MB
  ushort* Vtbf = Kbf + (size_t)2097152;          // (B,H,D,S) bf16, 4 MB

  char* ws = (char*)d_ws;
  ushort* Qbf   = (ushort*)ws;                   // 4 MB
  ushort* attnb = (ushort*)(ws + (4 << 20));     // 4 MB
  uint*   keep  = (uint*)(ws + (8 << 20));       // 1 MB
  ushort* Wtq   = (ushort*)(ws + (9 << 20));     // 0.5 MB
  ushort* Wto   = (ushort*)(ws + (9 << 20) + (512 << 10));  // 0.5 MB

  dim3 blk(256);
  prep_wt_kernel<<<dim3(64, 2), blk, 0, stream>>>(wq, wo, Wtq, Wto);
  prep_kv_kernel<<<dim3(512), blk, 0, stream>>>(keys, values, Kbf, Vtbf);
  prep_mask_kernel<<<dim3(1024), blk, 0, stream>>>(maskp, keep);
  proj_q_kernel<<<dim3(8, 64), blk, 0, stream>>>(inputs, Wtq, Qbf);
  flash_attn_kernel<<<dim3(512), blk, 0, stream>>>(Qbf, Kbf, Vtbf, keep, attnb);
  proj_out_kernel<<<dim3(8, 64), blk, 0, stream>>>(attnb, Wto, out);
}

// Round 8
// 169.118 us; speedup vs baseline: 1.1979x; 1.1979x over previous
//
#include <hip/hip_runtime.h>
#include <hip/hip_bf16.h>

namespace {

constexpr int B = 2, S = 2048, E = 512, H = 8, D = 64, HD = 512;
constexpr float SL = 0.125f * 1.44269504f;  // (1/sqrt(64)) * log2(e)
constexpr int PLD = 40;                     // proj LDS row stride (bf16)

typedef __attribute__((ext_vector_type(8))) short bf16x8;
typedef __attribute__((ext_vector_type(4))) unsigned short u16x4;
typedef __attribute__((ext_vector_type(4))) float f32x4;
typedef __attribute__((ext_vector_type(4))) float float4v;

__device__ __forceinline__ ushort f2b(float x) {
  __hip_bfloat16 h = __float2bfloat16(x);
  return *reinterpret_cast<const ushort*>(&h);
}

// ---------------------------------------------------------------------------
// Fused prep. blocks [0,512): K/V convert+transpose; [512,640): W transpose;
// [640,1664): mask -> keep bits.
__global__ __launch_bounds__(256) void prep_fused_kernel(
    const float* __restrict__ K, const float* __restrict__ V,
    const float* __restrict__ Wq, const float* __restrict__ Wo,
    const int* __restrict__ maskp,
    ushort* __restrict__ Kbf, ushort* __restrict__ Vtbf,
    ushort* __restrict__ Wtq, ushort* __restrict__ Wto,
    uint* __restrict__ keep) {
  const int bid = blockIdx.x;
  const int t = threadIdx.x;
  if (bid < 512) {
    __shared__ __align__(16) ushort Vn[64][76];
    const int kt = bid & 31;
    const int bh = bid >> 5;
    const int b = bh >> 3, h = bh & 7;
    const int k0 = kt * 64;
#pragma unroll
    for (int i = 0; i < 4; ++i) {
      int c = i * 256 + t;
      int kk = c >> 4, d4 = (c & 15) * 4;
      size_t g = ((size_t)(b * 2048 + k0 + kk) * 8 + h) * 64 + d4;
      float4v kv = *(const float4v*)(K + g);
      float4v vv = *(const float4v*)(V + g);
      u16x4 kp = {f2b(kv.x), f2b(kv.y), f2b(kv.z), f2b(kv.w)};
      u16x4 vp = {f2b(vv.x), f2b(vv.y), f2b(vv.z), f2b(vv.w)};
      *(u16x4*)(Kbf + ((size_t)(bh * 2048 + k0 + kk)) * 64 + d4) = kp;
      *(u16x4*)&Vn[kk][d4] = vp;
    }
    __syncthreads();
#pragma unroll
    for (int i = 0; i < 2; ++i) {
      int c = i * 256 + t;
      int kc8 = (c & 7) * 8, d = c >> 3;
      union { ushort u[8]; bf16x8 v; } p;
#pragma unroll
      for (int j = 0; j < 8; ++j) p.u[j] = Vn[kc8 + j][d];
      *(bf16x8*)(Vtbf + ((size_t)(bh * 64 + d)) * 2048 + k0 + kc8) = p.v;
    }
  } else if (bid < 640) {
    __shared__ __align__(16) ushort T[64][68];
    const int idx = bid - 512;
    const float* Wsrc = (idx >> 6) ? Wo : Wq;
    ushort* Wdst = (idx >> 6) ? Wto : Wtq;
    const int x = idx & 63;
    const int k0 = (x & 7) * 64, n0 = (x >> 3) * 64;
#pragma unroll
    for (int i = 0; i < 4; ++i) {
      int c = i * 256 + t;
      int kk = c >> 4, n4 = (c & 15) * 4;
      float4v v = *(const float4v*)(Wsrc + (size_t)(k0 + kk) * 512 + n0 + n4);
      u16x4 p = {f2b(v.x), f2b(v.y), f2b(v.z), f2b(v.w)};
      *(u16x4*)&T[kk][n4] = p;
    }
    __syncthreads();
#pragma unroll
    for (int i = 0; i < 2; ++i) {
      int c = i * 256 + t;
      int n = c >> 3, k8 = (c & 7) * 8;
      union { ushort u[8]; bf16x8 v; } p;
#pragma unroll
      for (int j = 0; j < 8; ++j) p.u[j] = T[k8 + j][n];
      *(bf16x8*)(Wdst + (size_t)(n0 + n) * 512 + k0 + k8) = p.v;
    }
  } else {
    int gid = (bid - 640) * 256 + t;  // 262144 total
    int row = gid >> 6, j = gid & 63;
    const int4* p = (const int4*)(maskp + (size_t)row * 2048 + j * 32);
    uint wv = 0;
#pragma unroll
    for (int q = 0; q < 8; ++q) {
      int4 v = p[q];
      wv |= (uint)(v.x == 0) << (q * 4 + 0);
      wv |= (uint)(v.y == 0) << (q * 4 + 1);
      wv |= (uint)(v.z == 0) << (q * 4 + 2);
      wv |= (uint)(v.w == 0) << (q * 4 + 3);
    }
    keep[gid] = wv;
  }
}

// ---------------------------------------------------------------------------
// proj_q: Qbf[b][h][q][d] (bf16) = inputs @ Wq, plain bf16 A, pipelined staging.
__global__ __launch_bounds__(256) void proj_q_kernel(
    const float* __restrict__ A, const ushort* __restrict__ Wt, ushort* __restrict__ Qbf) {
  __shared__ __align__(16) ushort As[64][PLD];
  __shared__ __align__(16) ushort Ws[64][PLD];

  const int tid = threadIdx.x;
  const int lane = tid & 63;
  const int w = tid >> 6;
  const int col = lane & 15;
  const int quad = lane >> 4;
  const int m0 = blockIdx.y * 64;
  const int n0 = blockIdx.x * 64;
  const int wm = (w & 1) * 32;
  const int wn = (w >> 1) * 32;
  const int ar = tid >> 2;
  const int ak = (tid & 3) * 8;
  const int wn2 = tid >> 2;
  const int wkc = (tid & 3) * 8;

  f32x4 acc[2][2];
#pragma unroll
  for (int i = 0; i < 2; ++i)
#pragma unroll
    for (int j = 0; j < 2; ++j) acc[i][j] = f32x4{0.f, 0.f, 0.f, 0.f};

  const float* Ap = A + (size_t)(m0 + ar) * 512 + ak;
  const ushort* Wp = Wt + (size_t)(n0 + wn2) * 512 + wkc;
  float4v a0p = *(const float4v*)Ap;
  float4v a1p = *(const float4v*)(Ap + 4);
  bf16x8 wp = *(const bf16x8*)Wp;

  for (int kt = 0; kt < 16; ++kt) {
    if (kt) __syncthreads();
    {
      union { ushort u[8]; bf16x8 v; } ap;
      ap.u[0] = f2b(a0p.x); ap.u[1] = f2b(a0p.y); ap.u[2] = f2b(a0p.z); ap.u[3] = f2b(a0p.w);
      ap.u[4] = f2b(a1p.x); ap.u[5] = f2b(a1p.y); ap.u[6] = f2b(a1p.z); ap.u[7] = f2b(a1p.w);
      *(bf16x8*)&As[ar][ak] = ap.v;
      *(bf16x8*)&Ws[wn2][wkc] = wp;
    }
    if (kt < 15) {
      const int k1 = (kt + 1) * 32;
      a0p = *(const float4v*)(Ap + k1);
      a1p = *(const float4v*)(Ap + k1 + 4);
      wp = *(const bf16x8*)(Wp + k1);
    }
    __syncthreads();

    bf16x8 ah[2], wb[2];
#pragma unroll
    for (int i = 0; i < 2; ++i)
      ah[i] = *(const bf16x8*)&As[wm + i * 16 + col][quad * 8];
#pragma unroll
    for (int j = 0; j < 2; ++j)
      wb[j] = *(const bf16x8*)&Ws[wn + j * 16 + col][quad * 8];
#pragma unroll
    for (int i = 0; i < 2; ++i)
#pragma unroll
      for (int j = 0; j < 2; ++j)
        acc[i][j] = __builtin_amdgcn_mfma_f32_16x16x32_bf16(ah[i], wb[j], acc[i][j], 0, 0, 0);
  }

#pragma unroll
  for (int i = 0; i < 2; ++i)
#pragma unroll
    for (int j = 0; j < 2; ++j)
#pragma unroll
      for (int r = 0; r < 4; ++r) {
        int m = m0 + wm + i * 16 + quad * 4 + r;
        int n = n0 + wn + j * 16 + col;
        int b = m >> 11, q = m & 2047, h = n >> 6, dd = n & 63;
        Qbf[((size_t)(b * 8 + h) * 2048 + q) * 64 + dd] = f2b(acc[i][j][r]);
      }
}

// ---------------------------------------------------------------------------
// proj_out: out fp32 = attnb (bf16) @ Wo, pipelined staging.
__global__ __launch_bounds__(256) void proj_out_kernel(
    const ushort* __restrict__ A, const ushort* __restrict__ Wt, float* __restrict__ C) {
  __shared__ __align__(16) ushort As[64][PLD];
  __shared__ __align__(16) ushort Ws[64][PLD];

  const int tid = threadIdx.x;
  const int lane = tid & 63;
  const int w = tid >> 6;
  const int col = lane & 15;
  const int quad = lane >> 4;
  const int m0 = blockIdx.y * 64;
  const int n0 = blockIdx.x * 64;
  const int wm = (w & 1) * 32;
  const int wn = (w >> 1) * 32;
  const int ar = tid >> 2;
  const int ak = (tid & 3) * 8;
  const int wn2 = tid >> 2;
  const int wkc = (tid & 3) * 8;

  f32x4 acc[2][2];
#pragma unroll
  for (int i = 0; i < 2; ++i)
#pragma unroll
    for (int j = 0; j < 2; ++j) acc[i][j] = f32x4{0.f, 0.f, 0.f, 0.f};

  const ushort* Ap = A + (size_t)(m0 + ar) * 512 + ak;
  const ushort* Wp = Wt + (size_t)(n0 + wn2) * 512 + wkc;
  bf16x8 apre = *(const bf16x8*)Ap;
  bf16x8 wp = *(const bf16x8*)Wp;

  for (int kt = 0; kt < 16; ++kt) {
    if (kt) __syncthreads();
    *(bf16x8*)&As[ar][ak] = apre;
    *(bf16x8*)&Ws[wn2][wkc] = wp;
    if (kt < 15) {
      const int k1 = (kt + 1) * 32;
      apre = *(const bf16x8*)(Ap + k1);
      wp = *(const bf16x8*)(Wp + k1);
    }
    __syncthreads();

    bf16x8 ah[2], wb[2];
#pragma unroll
    for (int i = 0; i < 2; ++i)
      ah[i] = *(const bf16x8*)&As[wm + i * 16 + col][quad * 8];
#pragma unroll
    for (int j = 0; j < 2; ++j)
      wb[j] = *(const bf16x8*)&Ws[wn + j * 16 + col][quad * 8];
#pragma unroll
    for (int i = 0; i < 2; ++i)
#pragma unroll
      for (int j = 0; j < 2; ++j)
        acc[i][j] = __builtin_amdgcn_mfma_f32_16x16x32_bf16(ah[i], wb[j], acc[i][j], 0, 0, 0);
  }

#pragma unroll
  for (int i = 0; i < 2; ++i)
#pragma unroll
    for (int j = 0; j < 2; ++j)
#pragma unroll
      for (int r = 0; r < 4; ++r)
        C[(size_t)(m0 + wm + i * 16 + quad * 4 + r) * 512 + n0 + wn + j * 16 + col] =
            acc[i][j][r];
}

// ---------------------------------------------------------------------------
// Flash attention, S^T orientation, register-prefetch pipelined K/V staging.
__global__ __launch_bounds__(256) void flash_attn_kernel(
    const ushort* __restrict__ Qbf, const ushort* __restrict__ Kbf,
    const ushort* __restrict__ Vtbf, const uint* __restrict__ keep,
    ushort* __restrict__ Op) {
  __shared__ __align__(16) ushort Ks[128][72];
  __shared__ __align__(16) ushort Vt[64][136];
  __shared__ __align__(16) ushort PQ[64][136];  // Q staged first; reused as P[q][k]

  const int bid = blockIdx.x;
  const int qt = bid & 31;
  const int bh = bid >> 5;
  const int b = bh >> 3, h = bh & 7;
  const int q0 = qt * 64;
  const int tid = threadIdx.x;
  const int lane = tid & 63;
  const int w = tid >> 6;
  const int col = lane & 15;
  const int quad = lane >> 4;
  const int quad4 = quad * 4;

  // stage Q (64x64 bf16, contiguous) into PQ[:][0..63]
  const ushort* Qt = Qbf + (size_t)(bh * 2048 + q0) * 64;
#pragma unroll
  for (int i = 0; i < 2; ++i) {
    int c = i * 256 + tid;
    *(bf16x8*)&PQ[c >> 3][(c & 7) * 8] = *(const bf16x8*)(Qt + c * 8);
  }
  __syncthreads();
  // hoist Q B-fragments (rows are this wave's own rows; safe vs later P writes)
  const bf16x8 qb0 = *(const bf16x8*)&PQ[w * 16 + col][quad * 8];
  const bf16x8 qb1 = *(const bf16x8*)&PQ[w * 16 + col][32 + quad * 8];

  f32x4 oacc[4];
#pragma unroll
  for (int c = 0; c < 4; ++c) oacc[c] = f32x4{0.f, 0.f, 0.f, 0.f};
  float m = -INFINITY, l = 0.f;

  const uint4* kr = (const uint4*)keep + ((size_t)(b * 2048 + q0 + w * 16 + col)) * 16;
  const ushort* Kbase = Kbf + (size_t)bh * 2048 * 64;
  const ushort* Vbase = Vtbf + (size_t)bh * 64 * 2048;

  // prefetch tile 0
  bf16x8 kpre[4], vpre[4];
  uint4 kw = kr[0];
#pragma unroll
  for (int i = 0; i < 4; ++i) {
    int c = i * 256 + tid;
    kpre[i] = *(const bf16x8*)(Kbase + (size_t)c * 8);
    int d = c >> 4, k8 = (c & 15) * 8;
    vpre[i] = *(const bf16x8*)(Vbase + (size_t)d * 2048 + k8);
  }

  for (int kt = 0; kt < 16; ++kt) {
    if (kt) __syncthreads();  // all waves done reading LDS for tile kt-1
    // store prefetched tile into LDS
#pragma unroll
    for (int i = 0; i < 4; ++i) {
      int c = i * 256 + tid;
      *(bf16x8*)&Ks[c >> 3][(c & 7) * 8] = kpre[i];
      int d = c >> 4, k8 = (c & 15) * 8;
      *(bf16x8*)&Vt[d][k8] = vpre[i];
    }
    // issue next tile's loads (latency hidden behind this tile's compute)
    uint4 kwn = kw;
    if (kt < 15) {
      const int k1 = (kt + 1) * 128;
      kwn = kr[kt + 1];
#pragma unroll
      for (int i = 0; i < 4; ++i) {
        int c = i * 256 + tid;
        kpre[i] = *(const bf16x8*)(Kbase + (size_t)k1 * 64 + c * 8);
        int d = c >> 4, k8 = (c & 15) * 8;
        vpre[i] = *(const bf16x8*)(Vbase + (size_t)d * 2048 + k1 + k8);
      }
    }
    __syncthreads();  // staging visible

    const uint mwords[4] = {kw.x, kw.y, kw.z, kw.w};

    // S^T: 128 k-rows x 16 q-cols per wave
    f32x4 sc[8];
#pragma unroll
    for (int t = 0; t < 8; ++t) sc[t] = f32x4{0.f, 0.f, 0.f, 0.f};
#pragma unroll
    for (int t = 0; t < 8; ++t) {
      bf16x8 ka0 = *(const bf16x8*)&Ks[t * 16 + col][quad * 8];
      bf16x8 ka1 = *(const bf16x8*)&Ks[t * 16 + col][32 + quad * 8];
      sc[t] = __builtin_amdgcn_mfma_f32_16x16x32_bf16(ka0, qb0, sc[t], 0, 0, 0);
      sc[t] = __builtin_amdgcn_mfma_f32_16x16x32_bf16(ka1, qb1, sc[t], 0, 0, 0);
    }

    // in-lane max over 32 raw scores, then 2 shuffles
    float mx = -INFINITY;
#pragma unroll
    for (int t = 0; t < 8; ++t)
#pragma unroll
      for (int r = 0; r < 4; ++r) mx = fmaxf(mx, sc[t][r]);
    mx *= SL;
    mx = fmaxf(mx, __shfl_xor(mx, 16));
    mx = fmaxf(mx, __shfl_xor(mx, 32));

    const float mn = fmaxf(m, mx);
    const float alpha = exp2f(m - mn);
    m = mn;

    float rs = 0.f;
#pragma unroll
    for (int t = 0; t < 8; ++t) {
      uint sh = mwords[t >> 1] >> ((t & 1) * 16 + quad4);
#pragma unroll
      for (int r = 0; r < 4; ++r) {
        float p = exp2f(fmaf(sc[t][r], SL, -mn));
        p = ((sh >> r) & 1u) ? p : 0.f;
        sc[t][r] = p;
        rs += p;
      }
    }
    rs += __shfl_xor(rs, 16);
    rs += __shfl_xor(rs, 32);
    l = l * alpha + rs;

    float alO[4];
#pragma unroll
    for (int r = 0; r < 4; ++r) alO[r] = __shfl(alpha, quad4 + r);
#pragma unroll
    for (int c = 0; c < 4; ++c)
#pragma unroll
      for (int r = 0; r < 4; ++r) oacc[c][r] *= alO[r];

    // store P transposed: PQ[q][k], 4 consecutive k per lane -> b64
#pragma unroll
    for (int t = 0; t < 8; ++t) {
      u16x4 pk = {f2b(sc[t][0]), f2b(sc[t][1]), f2b(sc[t][2]), f2b(sc[t][3])};
      *(u16x4*)&PQ[w * 16 + col][t * 16 + quad4] = pk;
    }
    __threadfence_block();

    bf16x8 pa[4];
#pragma unroll
    for (int kb = 0; kb < 4; ++kb)
      pa[kb] = *(const bf16x8*)&PQ[w * 16 + col][kb * 32 + quad * 8];
#pragma unroll
    for (int c = 0; c < 4; ++c)
#pragma unroll
      for (int kb = 0; kb < 4; ++kb) {
        bf16x8 vb = *(const bf16x8*)&Vt[c * 16 + col][kb * 32 + quad * 8];
        oacc[c] = __builtin_amdgcn_mfma_f32_16x16x32_bf16(pa[kb], vb, oacc[c], 0, 0, 0);
      }
    kw = kwn;
  }

  const float inv = 1.f / l;
  float invO[4];
#pragma unroll
  for (int r = 0; r < 4; ++r) invO[r] = __shfl(inv, quad4 + r);
#pragma unroll
  for (int c = 0; c < 4; ++c)
#pragma unroll
    for (int r = 0; r < 4; ++r)
      Op[(size_t)(b * S + q0 + w * 16 + quad4 + r) * HD + h * D + c * 16 + col] =
          f2b(oacc[c][r] * invO[r]);
}

}  // namespace

extern "C" void kernel_launch(void* const* d_in, const int* in_sizes, int n_in,
                              void* d_out, int out_size, void* d_ws, size_t ws_size,
                              hipStream_t stream) {
  const float* inputs = (const float*)d_in[0];   // (B,S,E)
  const float* keys   = (const float*)d_in[1];   // (B,S,H,D)
  const float* values = (const float*)d_in[2];   // (B,S,H,D)
  const float* wq     = (const float*)d_in[3];   // (E, HD)
  const float* wo     = (const float*)d_in[4];   // (HD, E)
  const int*   maskp  = (const int*)d_in[5];     // (B,S,S) bool as int32
  float* out = (float*)d_out;                    // (B,S,E)

  // d_out (8 MB) doubles as scratch for K/V bf16 until proj_out overwrites it.
  ushort* Kbf  = (ushort*)d_out;                 // (B,H,S,D) bf16, 4 MB
  ushort* Vtbf = Kbf + (size_t)2097152;          // (B,H,D,S) bf16, 4 MB

  char* ws = (char*)d_ws;
  ushort* Qbf   = (ushort*)ws;                   // 4 MB
  ushort* attnb = (ushort*)(ws + (4 << 20));     // 4 MB
  uint*   keep  = (uint*)(ws + (8 << 20));       // 1 MB
  ushort* Wtq   = (ushort*)(ws + (9 << 20));     // 0.5 MB
  ushort* Wto   = (ushort*)(ws + (9 << 20) + (512 << 10));  // 0.5 MB

  dim3 blk(256);
  prep_fused_kernel<<<dim3(1664), blk, 0, stream>>>(keys, values, wq, wo, maskp,
                                                    Kbf, Vtbf, Wtq, Wto, keep);
  proj_q_kernel<<<dim3(8, 64), blk, 0, stream>>>(inputs, Wtq, Qbf);
  flash_attn_kernel<<<dim3(512), blk, 0, stream>>>(Qbf, Kbf, Vtbf, keep, attnb);
  proj_out_kernel<<<dim3(8, 64), blk, 0, stream>>>(attnb, Wto, out);
}